// Round 6
// baseline (866.707 us; speedup 1.0000x reference)
//
#include <hip/hip_runtime.h>

#define N_NODES 500000

// ===========================================================================
// FAST PATH (R6): MSD two-level edge sort -> coalesced gathers.
//  level 1: dst-bucket = dst>>13 (8192 nodes, NB=62).  rec1 = dl13<<19 | src19
//  level 2: within bucket, bin by srcGroup = src>>7 (G=3907). rec2 = src19<<13 | dl13
//  Aggregation: WG-per-(bucket,sub) with LDS acc + partials + reduce.
// ===========================================================================
#define BK      8192
#define BKBITS  13
#define NB      62          // ceil(500000/8192)
#define SPLIT   9           // sub-WGs per bucket
#define G       3907        // ceil(500000/128)
#define GBITS   7
#define C1      8192        // edges per level-1 chunk
#define SRC19   0x7FFFFu

typedef unsigned int u32;

// ---- level-1 count: per-chunk histogram over 62 dst-buckets
__global__ __launch_bounds__(1024) void k_count1(
        const int* __restrict__ dst, int E,
        u32* __restrict__ counts1, u32* __restrict__ aux1) {
    __shared__ u32 hist[NB];
    int tid = threadIdx.x, bid = blockIdx.x;
    if (tid < NB) hist[tid] = 0;
    __syncthreads();
    int e0 = bid * C1, e1 = min(E, e0 + C1);
    for (int e = e0 + tid; e < e1; e += 1024)
        atomicAdd(&hist[((u32)dst[e]) >> BKBITS], 1u);
    __syncthreads();
    if (tid < NB) aux1[(size_t)bid * NB + tid] = atomicAdd(&counts1[tid], hist[tid]);
}

// ---- level-1 scan (62 entries; serial, trivial)
__global__ void k_scan1(const u32* __restrict__ counts1, u32* __restrict__ bb1) {
    if (threadIdx.x == 0) {
        u32 a = 0;
        for (int b = 0; b < NB; ++b) { bb1[b] = a; a += counts1[b]; }
        bb1[NB] = a;
    }
}

// ---- level-1 scatter with LDS presort -> coalesced rec1 writes
__global__ __launch_bounds__(1024) void k_scatter1(
        const int* __restrict__ src, const int* __restrict__ dst, int E,
        const u32* __restrict__ bb1, const u32* __restrict__ aux1,
        u32* __restrict__ rec1) {
    __shared__ u32 srec[C1];
    __shared__ unsigned char sbk[C1];
    __shared__ u32 hist[NB], scn[NB], cur[NB];
    int tid = threadIdx.x, bid = blockIdx.x;
    if (tid < NB) hist[tid] = 0;
    __syncthreads();
    int e0 = bid * C1, e1 = min(E, e0 + C1), n = e1 - e0;
    for (int e = e0 + tid; e < e1; e += 1024)
        atomicAdd(&hist[((u32)dst[e]) >> BKBITS], 1u);
    __syncthreads();
    if (tid == 0) {
        u32 a = 0;
        for (int b = 0; b < NB; ++b) { scn[b] = a; a += hist[b]; }
    }
    __syncthreads();
    if (tid < NB) cur[tid] = scn[tid];
    __syncthreads();
    for (int e = e0 + tid; e < e1; e += 1024) {
        u32 d = (u32)dst[e], s = (u32)src[e], b = d >> BKBITS;
        u32 p = atomicAdd(&cur[b], 1u);
        srec[p] = ((d & (BK - 1u)) << 19) | s;
        sbk[p] = (unsigned char)b;
    }
    __syncthreads();
    const u32* row = aux1 + (size_t)bid * NB;
    for (int p = tid; p < n; p += 1024) {
        int b = sbk[p];
        rec1[bb1[b] + row[b] + ((u32)p - scn[b])] = srec[p];   // coalesced runs
    }
}

// ---- level-2 count (per (bucket,sub) range) + fused degree histogram
__global__ __launch_bounds__(1024) void k_count2deg(
        const u32* __restrict__ rec1, const u32* __restrict__ bb1,
        u32* __restrict__ counts2, u32* __restrict__ aux2,
        u32* __restrict__ degp) {
    __shared__ u32 hist[G];
    __shared__ u32 cnt[BK];
    int bid2 = blockIdx.x, b = bid2 / SPLIT, sub = bid2 % SPLIT, tid = threadIdx.x;
    for (int i = tid; i < G; i += 1024) hist[i] = 0;
    for (int i = tid; i < BK; i += 1024) cnt[i] = 0;
    __syncthreads();
    u32 base = bb1[b], len = bb1[b + 1] - base, per = (len + SPLIT - 1) / SPLIT;
    u32 s0 = base + (u32)sub * per;
    u32 end = base + len;
    u32 s1 = (s0 + per < end) ? (s0 + per) : end;
    for (u32 e = s0 + tid; e < s1; e += 1024) {
        u32 r = rec1[e];
        atomicAdd(&hist[(r & SRC19) >> GBITS], 1u);
        atomicAdd(&cnt[r >> 19], 1u);
    }
    __syncthreads();
    for (int g = tid; g < G; g += 1024)
        aux2[(size_t)bid2 * G + g] = atomicAdd(&counts2[(size_t)b * G + g], hist[g]);
    for (int l = tid; l < BK; l += 1024)
        degp[((size_t)bid2 << BKBITS) + l] = cnt[l];
}

// ---- level-2 scan: per-bucket exclusive prefix over G group counts
__global__ __launch_bounds__(1024) void k_scan2(
        const u32* __restrict__ counts2, const u32* __restrict__ bb1,
        u32* __restrict__ gbase) {
    __shared__ u32 ssum[1024];
    int b = blockIdx.x, tid = threadIdx.x;
    const u32* c = counts2 + (size_t)b * G;
    int i0 = tid * 4;
    u32 v[4], s = 0;
#pragma unroll
    for (int j = 0; j < 4; ++j) {
        u32 x = (i0 + j < G) ? c[i0 + j] : 0u;
        v[j] = s; s += x;
    }
    ssum[tid] = s;
    __syncthreads();
    for (int off = 1; off < 1024; off <<= 1) {
        u32 t = (tid >= off) ? ssum[tid - off] : 0u;
        __syncthreads();
        ssum[tid] += t;
        __syncthreads();
    }
    u32 base = bb1[b] + ssum[tid] - s;   // exclusive
#pragma unroll
    for (int j = 0; j < 4; ++j)
        if (i0 + j < G) gbase[(size_t)b * G + i0 + j] = base + v[j];
}

// ---- degree reduce -> dis = rsqrt(deg+1), m1 = dis*x
__global__ void k_reduce_deg(const u32* __restrict__ degp,
                             const float* __restrict__ x,
                             float* __restrict__ dis, float* __restrict__ m1) {
    int b = blockIdx.x >> 3, q = blockIdx.x & 7;
    int l = (q << 10) + threadIdx.x;
    int node = (b << BKBITS) + l;
    if (node >= N_NODES) return;
    u32 s = 0;
#pragma unroll
    for (int k = 0; k < SPLIT; ++k)
        s += degp[((size_t)(b * SPLIT + k) << BKBITS) + l];
    float r = rsqrtf((float)(s + 1u));     // +1 self-loop
    dis[node] = r;
    m1[node] = r * x[node];
}

// ---- level-2 scatter: rec1 (bucket region) -> rec2 sorted by srcGroup
__global__ __launch_bounds__(1024) void k_scatter2(
        const u32* __restrict__ rec1, const u32* __restrict__ bb1,
        const u32* __restrict__ gbase, const u32* __restrict__ aux2,
        u32* __restrict__ rec2) {
    __shared__ u32 cur[G];
    int bid2 = blockIdx.x, b = bid2 / SPLIT, sub = bid2 % SPLIT, tid = threadIdx.x;
    for (int g = tid; g < G; g += 1024)
        cur[g] = gbase[(size_t)b * G + g] + aux2[(size_t)bid2 * G + g];
    __syncthreads();
    u32 base = bb1[b], len = bb1[b + 1] - base, per = (len + SPLIT - 1) / SPLIT;
    u32 s0 = base + (u32)sub * per;
    u32 end = base + len;
    u32 s1 = (s0 + per < end) ? (s0 + per) : end;
    for (u32 e = s0 + tid; e < s1; e += 1024) {
        u32 r = rec1[e], sr = r & SRC19, g = sr >> GBITS;
        u32 p = atomicAdd(&cur[g], 1u);
        rec2[p] = (sr << BKBITS) | (r >> 19);
    }
}

// ---- layer-1 aggregation: coalesced m1 gathers (src-sorted), LDS acc
__global__ __launch_bounds__(1024) void k_layer1(
        const u32* __restrict__ rec2, const u32* __restrict__ bb1,
        const float* __restrict__ m1, float* __restrict__ accp) {
    __shared__ float acc[BK];
    int bid2 = blockIdx.x, b = bid2 / SPLIT, sub = bid2 % SPLIT, tid = threadIdx.x;
    for (int l = tid; l < BK; l += 1024) acc[l] = 0.f;
    __syncthreads();
    u32 base = bb1[b], len = bb1[b + 1] - base, per = (len + SPLIT - 1) / SPLIT;
    u32 s0 = base + (u32)sub * per;
    u32 end = base + len;
    u32 s1 = (s0 + per < end) ? (s0 + per) : end;
    for (u32 e = s0 + tid; e < s1; e += 1024) {
        u32 r = rec2[e];
        atomicAdd(&acc[r & (BK - 1u)], m1[r >> BKBITS]);
    }
    __syncthreads();
    for (int l = tid; l < BK; l += 1024)
        accp[((size_t)bid2 << BKBITS) + l] = acc[l];
}

// ---- reduce layer-1 partials, per-node MLP, write h2m + out(self+bias)
__global__ void k_reduce1(const float* __restrict__ accp,
                          const float* __restrict__ dis,
                          const float* __restrict__ m1,
                          const float* __restrict__ W1, const float* __restrict__ b1,
                          const float* __restrict__ W2, const float* __restrict__ b2,
                          float2* __restrict__ h2m, float2* __restrict__ out) {
    int b = blockIdx.x >> 3, q = blockIdx.x & 7;
    int l = (q << 10) + threadIdx.x;
    int node = (b << BKBITS) + l;
    if (node >= N_NODES) return;
    float s = 0.f;
#pragma unroll
    for (int k = 0; k < SPLIT; ++k)
        s += accp[((size_t)(b * SPLIT + k) << BKBITS) + l];
    float d = dis[node];
    float sf = d * (s + m1[node]);
    float a0 = 0.f, a1 = 0.f;
#pragma unroll
    for (int k = 0; k < 8; ++k) {
        float h = fmaxf(W1[k] * sf + b1[k], 0.f);
        a0 += h * W2[2 * k + 0];
        a1 += h * W2[2 * k + 1];
    }
    h2m[node] = make_float2(d * a0, d * a1);
    out[node] = make_float2(b2[0] + d * d * a0, b2[1] + d * d * a1);
}

// ---- layer-2 aggregation: coalesced h2m gathers, two LDS planes
__global__ __launch_bounds__(1024) void k_layer2b(
        const u32* __restrict__ rec2, const u32* __restrict__ bb1,
        const float2* __restrict__ h2m,
        float* __restrict__ px, float* __restrict__ py) {
    __shared__ float ax[BK];
    __shared__ float ay[BK];
    int bid2 = blockIdx.x, b = bid2 / SPLIT, sub = bid2 % SPLIT, tid = threadIdx.x;
    for (int l = tid; l < BK; l += 1024) { ax[l] = 0.f; ay[l] = 0.f; }
    __syncthreads();
    u32 base = bb1[b], len = bb1[b + 1] - base, per = (len + SPLIT - 1) / SPLIT;
    u32 s0 = base + (u32)sub * per;
    u32 end = base + len;
    u32 s1 = (s0 + per < end) ? (s0 + per) : end;
    for (u32 e = s0 + tid; e < s1; e += 1024) {
        u32 r = rec2[e];
        float2 v = h2m[r >> BKBITS];
        u32 dl = r & (BK - 1u);
        atomicAdd(&ax[dl], v.x);
        atomicAdd(&ay[dl], v.y);
    }
    __syncthreads();
    for (int l = tid; l < BK; l += 1024) {
        px[((size_t)bid2 << BKBITS) + l] = ax[l];
        py[((size_t)bid2 << BKBITS) + l] = ay[l];
    }
}

// ---- reduce layer-2 partials: out += dis * sum
__global__ void k_reduce2(const float* __restrict__ px, const float* __restrict__ py,
                          const float* __restrict__ dis, float2* __restrict__ out) {
    int b = blockIdx.x >> 3, q = blockIdx.x & 7;
    int l = (q << 10) + threadIdx.x;
    int node = (b << BKBITS) + l;
    if (node >= N_NODES) return;
    float sx = 0.f, sy = 0.f;
#pragma unroll
    for (int k = 0; k < SPLIT; ++k) {
        size_t idx = ((size_t)(b * SPLIT + k) << BKBITS) + l;
        sx += px[idx];
        sy += py[idx];
    }
    float d = dis[node];
    float2 o = out[node];
    out[node] = make_float2(o.x + d * sx, o.y + d * sy);
}

// ===========================================================================
// MID PATH (R5 kernels): 1024-node dst buckets, unsorted gathers.
// Used when workspace is too small for the fast path.
// ===========================================================================
#define NPB 1024
#define NBUCK ((N_NODES + NPB - 1) / NPB)   // 489
#define BIN_CHUNK 32768
#define BTB 1024
#define SRCMASK 0x3FFFFFu

typedef int  v4i __attribute__((ext_vector_type(4)));
typedef unsigned int v4u __attribute__((ext_vector_type(4)));

__device__ inline v4i nt_load4i(const int* p) { return __builtin_nontemporal_load((const v4i*)p); }
__device__ inline v4u nt_load4u(const u32* p) { return __builtin_nontemporal_load((const v4u*)p); }
__device__ inline int nt_load1i(const int* p) { return __builtin_nontemporal_load(p); }
__device__ inline u32 nt_load1u(const u32* p) { return __builtin_nontemporal_load(p); }

__global__ __launch_bounds__(BTB) void k_bin_count(
        const int* __restrict__ dst, int E, u32* __restrict__ counts, u32* __restrict__ aux) {
    __shared__ u32 hist[NBUCK];
    int tid = threadIdx.x, bid = blockIdx.x;
    for (int b = tid; b < NBUCK; b += BTB) hist[b] = 0;
    __syncthreads();
    int e0 = bid * BIN_CHUNK, e1 = min(E, e0 + BIN_CHUNK);
    int nv = (e1 - e0) >> 2;
    for (int i = tid; i < nv; i += BTB) {
        v4i d = nt_load4i(dst + e0 + (i << 2));
        atomicAdd(&hist[(u32)d.x >> 10], 1u);
        atomicAdd(&hist[(u32)d.y >> 10], 1u);
        atomicAdd(&hist[(u32)d.z >> 10], 1u);
        atomicAdd(&hist[(u32)d.w >> 10], 1u);
    }
    for (int e = e0 + (nv << 2) + tid; e < e1; e += BTB)
        atomicAdd(&hist[(u32)nt_load1i(dst + e) >> 10], 1u);
    __syncthreads();
    u32* row = aux + (size_t)bid * NBUCK;
    for (int b = tid; b < NBUCK; b += BTB)
        row[b] = atomicAdd(&counts[b], hist[b]);
}

__global__ void k_scan(const u32* __restrict__ counts, u32* __restrict__ bucket_base) {
    __shared__ u32 sc[512];
    int tid = threadIdx.x;
    u32 v = (tid < NBUCK) ? counts[tid] : 0u;
    sc[tid] = v;
    __syncthreads();
    for (int off = 1; off < 512; off <<= 1) {
        u32 t = (tid >= off) ? sc[tid - off] : 0u;
        __syncthreads();
        sc[tid] += t;
        __syncthreads();
    }
    if (tid <= NBUCK) bucket_base[tid] = sc[tid] - v;
}

__global__ __launch_bounds__(BTB) void k_bin_scatter(
        const int* __restrict__ src, const int* __restrict__ dst, int E,
        const u32* __restrict__ bucket_base, const u32* __restrict__ aux,
        u32* __restrict__ rec) {
    __shared__ u32 cur[NBUCK];
    int tid = threadIdx.x, bid = blockIdx.x;
    const u32* row = aux + (size_t)bid * NBUCK;
    for (int b = tid; b < NBUCK; b += BTB) cur[b] = bucket_base[b] + row[b];
    __syncthreads();
    int e0 = bid * BIN_CHUNK, e1 = min(E, e0 + BIN_CHUNK);
    int nv = (e1 - e0) >> 2;
    for (int i = tid; i < nv; i += BTB) {
        v4i d = nt_load4i(dst + e0 + (i << 2));
        v4i s = nt_load4i(src + e0 + (i << 2));
        u32 p0 = atomicAdd(&cur[(u32)d.x >> 10], 1u);
        u32 p1 = atomicAdd(&cur[(u32)d.y >> 10], 1u);
        u32 p2 = atomicAdd(&cur[(u32)d.z >> 10], 1u);
        u32 p3 = atomicAdd(&cur[(u32)d.w >> 10], 1u);
        rec[p0] = (((u32)d.x & (NPB - 1u)) << 22) | (u32)s.x;
        rec[p1] = (((u32)d.y & (NPB - 1u)) << 22) | (u32)s.y;
        rec[p2] = (((u32)d.z & (NPB - 1u)) << 22) | (u32)s.z;
        rec[p3] = (((u32)d.w & (NPB - 1u)) << 22) | (u32)s.w;
    }
    for (int e = e0 + (nv << 2) + tid; e < e1; e += BTB) {
        u32 d = (u32)nt_load1i(dst + e);
        u32 p = atomicAdd(&cur[d >> 10], 1u);
        rec[p] = ((d & (NPB - 1u)) << 22) | (u32)nt_load1i(src + e);
    }
}

__global__ __launch_bounds__(BTB) void k_deg_dis(
        const u32* __restrict__ rec, const u32* __restrict__ bucket_base,
        const float* __restrict__ x, float* __restrict__ dis, float* __restrict__ m1) {
    __shared__ u32 cnt[NPB];
    int tid = threadIdx.x, bid = blockIdx.x;
    for (int l = tid; l < NPB; l += BTB) cnt[l] = 0;
    __syncthreads();
    u32 e0 = bucket_base[bid], e1 = bucket_base[bid + 1];
    u32 ha = min((e0 + 3u) & ~3u, e1);
    u32 ta = (e1 & ~3u) > ha ? (e1 & ~3u) : ha;
    if (e0 + tid < ha) atomicAdd(&cnt[nt_load1u(rec + e0 + tid) >> 22], 1u);
    for (u32 i = (ha >> 2) + tid; i < (ta >> 2); i += BTB) {
        v4u r = nt_load4u(rec + (i << 2));
        atomicAdd(&cnt[r.x >> 22], 1u);
        atomicAdd(&cnt[r.y >> 22], 1u);
        atomicAdd(&cnt[r.z >> 22], 1u);
        atomicAdd(&cnt[r.w >> 22], 1u);
    }
    if (ta + tid < e1) atomicAdd(&cnt[nt_load1u(rec + ta + tid) >> 22], 1u);
    __syncthreads();
    int node0 = bid << 10;
    int nn = min(NPB, N_NODES - node0);
    for (int l = tid; l < nn; l += BTB) {
        int node = node0 + l;
        float r = rsqrtf((float)(cnt[l] + 1u));
        dis[node] = r;
        m1[node] = r * x[node];
    }
}

__global__ __launch_bounds__(BTB) void k_layer1_mid(
        const u32* __restrict__ rec, const u32* __restrict__ bucket_base,
        const float* __restrict__ dis, const float* __restrict__ m1,
        const float* __restrict__ W1, const float* __restrict__ b1,
        const float* __restrict__ W2, const float* __restrict__ b2,
        float2* __restrict__ h2m, float2* __restrict__ out) {
    __shared__ float acc[NPB];
    int tid = threadIdx.x, bid = blockIdx.x;
    for (int l = tid; l < NPB; l += BTB) acc[l] = 0.f;
    __syncthreads();
    u32 e0 = bucket_base[bid], e1 = bucket_base[bid + 1];
    u32 ha = min((e0 + 3u) & ~3u, e1);
    u32 ta = (e1 & ~3u) > ha ? (e1 & ~3u) : ha;
    if (e0 + tid < ha) {
        u32 r = nt_load1u(rec + e0 + tid);
        atomicAdd(&acc[r >> 22], m1[r & SRCMASK]);
    }
    for (u32 i = (ha >> 2) + tid; i < (ta >> 2); i += BTB) {
        v4u r = nt_load4u(rec + (i << 2));
        float v0 = m1[r.x & SRCMASK];
        float v1 = m1[r.y & SRCMASK];
        float v2 = m1[r.z & SRCMASK];
        float v3 = m1[r.w & SRCMASK];
        atomicAdd(&acc[r.x >> 22], v0);
        atomicAdd(&acc[r.y >> 22], v1);
        atomicAdd(&acc[r.z >> 22], v2);
        atomicAdd(&acc[r.w >> 22], v3);
    }
    if (ta + tid < e1) {
        u32 r = nt_load1u(rec + ta + tid);
        atomicAdd(&acc[r >> 22], m1[r & SRCMASK]);
    }
    __syncthreads();
    int node0 = bid << 10;
    int nn = min(NPB, N_NODES - node0);
    for (int l = tid; l < nn; l += BTB) {
        int node = node0 + l;
        float d = dis[node];
        float s = d * (acc[l] + m1[node]);
        float a0 = 0.f, a1 = 0.f;
#pragma unroll
        for (int k = 0; k < 8; ++k) {
            float h = fmaxf(W1[k] * s + b1[k], 0.f);
            a0 += h * W2[2 * k + 0];
            a1 += h * W2[2 * k + 1];
        }
        h2m[node] = make_float2(d * a0, d * a1);
        out[node] = make_float2(b2[0] + d * d * a0, b2[1] + d * d * a1);
    }
}

__global__ __launch_bounds__(BTB) void k_layer2_mid(
        const u32* __restrict__ rec, const u32* __restrict__ bucket_base,
        const float* __restrict__ dis, const float2* __restrict__ h2m,
        float2* __restrict__ out) {
    __shared__ float ax[NPB];
    __shared__ float ay[NPB];
    int tid = threadIdx.x, bid = blockIdx.x;
    for (int l = tid; l < NPB; l += BTB) { ax[l] = 0.f; ay[l] = 0.f; }
    __syncthreads();
    u32 e0 = bucket_base[bid], e1 = bucket_base[bid + 1];
    u32 ha = min((e0 + 3u) & ~3u, e1);
    u32 ta = (e1 & ~3u) > ha ? (e1 & ~3u) : ha;
    if (e0 + tid < ha) {
        u32 r = nt_load1u(rec + e0 + tid);
        float2 v = h2m[r & SRCMASK];
        atomicAdd(&ax[r >> 22], v.x);
        atomicAdd(&ay[r >> 22], v.y);
    }
    for (u32 i = (ha >> 2) + tid; i < (ta >> 2); i += BTB) {
        v4u r = nt_load4u(rec + (i << 2));
        float2 v0 = h2m[r.x & SRCMASK];
        float2 v1 = h2m[r.y & SRCMASK];
        float2 v2 = h2m[r.z & SRCMASK];
        float2 v3 = h2m[r.w & SRCMASK];
        atomicAdd(&ax[r.x >> 22], v0.x);
        atomicAdd(&ay[r.x >> 22], v0.y);
        atomicAdd(&ax[r.y >> 22], v1.x);
        atomicAdd(&ay[r.y >> 22], v1.y);
        atomicAdd(&ax[r.z >> 22], v2.x);
        atomicAdd(&ay[r.z >> 22], v2.y);
        atomicAdd(&ax[r.w >> 22], v3.x);
        atomicAdd(&ay[r.w >> 22], v3.y);
    }
    if (ta + tid < e1) {
        u32 r = nt_load1u(rec + ta + tid);
        float2 v = h2m[r & SRCMASK];
        atomicAdd(&ax[r >> 22], v.x);
        atomicAdd(&ay[r >> 22], v.y);
    }
    __syncthreads();
    int node0 = bid << 10;
    int nn = min(NPB, N_NODES - node0);
    for (int l = tid; l < nn; l += BTB) {
        int node = node0 + l;
        float d = dis[node];
        float2 o = out[node];
        out[node] = make_float2(o.x + d * ax[l], o.y + d * ay[l]);
    }
}

// ===========================================================================
extern "C" void kernel_launch(void* const* d_in, const int* in_sizes, int n_in,
                              void* d_out, int out_size, void* d_ws, size_t ws_size,
                              hipStream_t stream) {
    const float* x  = (const float*)d_in[0];
    const int*   ei = (const int*)d_in[1];   // [2, E]: src row, then dst row
    const float* W1 = (const float*)d_in[2];
    const float* b1 = (const float*)d_in[3];
    const float* W2 = (const float*)d_in[4];
    const float* b2 = (const float*)d_in[5];

    const int N = N_NODES;
    const int E = in_sizes[1] / 2;
    const int* src = ei;
    const int* dst = ei + E;
    float* out = (float*)d_out;
    char* ws = (char*)d_ws;

    // ---------------- fast-path workspace layout ----------------
    const int nchunks1 = (E + C1 - 1) / C1;
    size_t off = 0;
    auto take = [&](size_t bytes) { size_t o = off; off = (off + bytes + 255) & ~(size_t)255; return o; };
    size_t off_bb1    = take((NB + 1) * 4);
    size_t off_cnt1   = take(NB * 4);
    size_t off_cnt2   = take((size_t)NB * G * 4);
    size_t off_gbase  = take((size_t)NB * G * 4);
    size_t off_aux1   = take((size_t)nchunks1 * NB * 4);
    size_t off_aux2   = take((size_t)NB * SPLIT * G * 4);
    size_t off_dis    = take((size_t)N * 4);
    size_t off_m1     = take((size_t)N * 4);
    size_t off_h2m    = take((size_t)N * 8);
    size_t off_bufA   = take((size_t)NB * SPLIT * BK * 4);
    size_t off_bufB   = take((size_t)NB * SPLIT * BK * 4);
    size_t off_rec1   = take((size_t)E * 4);
    size_t off_rec2   = take((size_t)E * 4);
    size_t need_big   = off;

    if (ws_size >= need_big) {
        u32* bb1     = (u32*)(ws + off_bb1);
        u32* counts1 = (u32*)(ws + off_cnt1);
        u32* counts2 = (u32*)(ws + off_cnt2);
        u32* gbase   = (u32*)(ws + off_gbase);
        u32* aux1    = (u32*)(ws + off_aux1);
        u32* aux2    = (u32*)(ws + off_aux2);
        float* dis   = (float*)(ws + off_dis);
        float* m1    = (float*)(ws + off_m1);
        float2* h2m  = (float2*)(ws + off_h2m);
        float* bufA  = (float*)(ws + off_bufA);
        float* bufB  = (float*)(ws + off_bufB);
        u32* rec1    = (u32*)(ws + off_rec1);
        u32* rec2    = (u32*)(ws + off_rec2);

        hipMemsetAsync(counts1, 0, NB * 4, stream);
        hipMemsetAsync(counts2, 0, (size_t)NB * G * 4, stream);

        k_count1  <<<nchunks1,   1024, 0, stream>>>(dst, E, counts1, aux1);
        k_scan1   <<<1,            64, 0, stream>>>(counts1, bb1);
        k_scatter1<<<nchunks1,   1024, 0, stream>>>(src, dst, E, bb1, aux1, rec1);
        k_count2deg<<<NB * SPLIT,1024, 0, stream>>>(rec1, bb1, counts2, aux2,
                                                    (u32*)bufA);
        k_scan2   <<<NB,         1024, 0, stream>>>(counts2, bb1, gbase);
        k_reduce_deg<<<NB * 8,   1024, 0, stream>>>((u32*)bufA, x, dis, m1);
        k_scatter2<<<NB * SPLIT, 1024, 0, stream>>>(rec1, bb1, gbase, aux2, rec2);
        k_layer1  <<<NB * SPLIT, 1024, 0, stream>>>(rec2, bb1, m1, bufA);
        k_reduce1 <<<NB * 8,     1024, 0, stream>>>(bufA, dis, m1, W1, b1, W2, b2,
                                                    h2m, (float2*)out);
        k_layer2b <<<NB * SPLIT, 1024, 0, stream>>>(rec2, bb1, h2m, bufA, bufB);
        k_reduce2 <<<NB * 8,     1024, 0, stream>>>(bufA, bufB, dis, (float2*)out);
        return;
    }

    // ---------------- mid path (R5) ----------------
    const int nchunks = (E + BIN_CHUNK - 1) / BIN_CHUNK;
    size_t moff_counts = 0;
    size_t moff_bb     = 4096;
    size_t moff_aux    = 8192;
    size_t maux_bytes  = (size_t)nchunks * NBUCK * 4;
    size_t moff_dis    = (moff_aux + maux_bytes + 255) & ~(size_t)255;
    size_t moff_m1     = moff_dis + (size_t)N * 4;
    size_t moff_h2m    = moff_m1 + (size_t)N * 4;
    size_t moff_rec    = moff_h2m + (size_t)N * 8;

    u32* counts = (u32*)(ws + moff_counts);
    u32* bb     = (u32*)(ws + moff_bb);
    u32* aux    = (u32*)(ws + moff_aux);
    float* dis  = (float*)(ws + moff_dis);
    float* m1   = (float*)(ws + moff_m1);
    float2* h2m = (float2*)(ws + moff_h2m);
    u32* rec    = (u32*)(ws + moff_rec);

    hipMemsetAsync(counts, 0, NBUCK * 4, stream);
    k_bin_count  <<<nchunks, BTB, 0, stream>>>(dst, E, counts, aux);
    k_scan       <<<1,       512, 0, stream>>>(counts, bb);
    k_bin_scatter<<<nchunks, BTB, 0, stream>>>(src, dst, E, bb, aux, rec);
    k_deg_dis    <<<NBUCK,   BTB, 0, stream>>>(rec, bb, x, dis, m1);
    k_layer1_mid <<<NBUCK,   BTB, 0, stream>>>(rec, bb, dis, m1, W1, b1, W2, b2,
                                               h2m, (float2*)out);
    k_layer2_mid <<<NBUCK,   BTB, 0, stream>>>(rec, bb, dis, h2m, (float2*)out);
}

// Round 7
// 818.625 us; speedup vs baseline: 1.0587x; 1.0587x over previous
//
#include <hip/hip_runtime.h>

#define N_NODES 500000
typedef unsigned int u32;

// ===========================================================================
// FAST PATH (R7): 2-D (dstBucket x srcBucket) tiling, B=4096.
//   sort pass 1: by dst>>12 (123 buckets).  rec1 = dl12<<19 | src19
//   sort pass 2: by src>>12 within bucket.  rec2 = sl12<<12 | dl12
//   aggregation: WG=(dstBucket,srcRange); stage src window in LDS (coalesced),
//   per edge: ds_read window[sl] + ds_add acc[dl].  NO divergent global loads.
// ===========================================================================
#define B2BITS 12
#define B2     4096
#define NB2    123                    // ceil(500000/4096)
#define NPAD   (NB2 * B2)             // 503808 (padded node tables)
#define SPL    5                      // splits per bucket (sort + agg + partials)
#define JT     25                     // ceil(NB2/SPL) src-buckets per agg WG
#define C1     8192                   // edges per level-1 chunk
#define NT     1024
#define SRC19  0x7FFFFu

// ---- level-1 count: per-chunk histogram over 123 dst-buckets
__global__ __launch_bounds__(NT) void k_count1(
        const int* __restrict__ dst, int E,
        u32* __restrict__ counts1, u32* __restrict__ aux1) {
    __shared__ u32 hist[NB2];
    int tid = threadIdx.x, bid = blockIdx.x;
    if (tid < NB2) hist[tid] = 0;
    __syncthreads();
    int e0 = bid * C1, e1 = min(E, e0 + C1);
    for (int e = e0 + tid; e < e1; e += NT)
        atomicAdd(&hist[((u32)__builtin_nontemporal_load(dst + e)) >> B2BITS], 1u);
    __syncthreads();
    if (tid < NB2)
        aux1[(size_t)bid * NB2 + tid] = atomicAdd(&counts1[tid], hist[tid]);
}

// ---- level-1 scan (LDS-assisted serial over 123)
__global__ void k_scan1(const u32* __restrict__ counts1, u32* __restrict__ bb1) {
    __shared__ u32 c[NB2];
    int tid = threadIdx.x;
    if (tid < NB2) c[tid] = counts1[tid];
    __syncthreads();
    if (tid == 0) {
        u32 a = 0;
        for (int b = 0; b < NB2; ++b) { bb1[b] = a; a += c[b]; }
        bb1[NB2] = a;
    }
}

// ---- level-1 scatter with LDS presort -> coalesced rec1 writes
__global__ __launch_bounds__(NT) void k_scatter1(
        const int* __restrict__ src, const int* __restrict__ dst, int E,
        const u32* __restrict__ bb1, const u32* __restrict__ aux1,
        u32* __restrict__ rec1) {
    __shared__ u32 srec[C1];            // 32 KB
    __shared__ unsigned char sbk[C1];   // 8 KB
    __shared__ u32 hist[NB2], scn[NB2], cur[NB2];
    int tid = threadIdx.x, bid = blockIdx.x;
    if (tid < NB2) hist[tid] = 0;
    __syncthreads();
    int e0 = bid * C1, e1 = min(E, e0 + C1), n = e1 - e0;
    for (int e = e0 + tid; e < e1; e += NT)
        atomicAdd(&hist[((u32)__builtin_nontemporal_load(dst + e)) >> B2BITS], 1u);
    __syncthreads();
    if (tid == 0) {
        u32 a = 0;
        for (int b = 0; b < NB2; ++b) { scn[b] = a; a += hist[b]; }
    }
    __syncthreads();
    if (tid < NB2) cur[tid] = scn[tid];
    __syncthreads();
    for (int e = e0 + tid; e < e1; e += NT) {
        u32 d = (u32)__builtin_nontemporal_load(dst + e);
        u32 s = (u32)__builtin_nontemporal_load(src + e);
        u32 b = d >> B2BITS;
        u32 p = atomicAdd(&cur[b], 1u);
        srec[p] = ((d & (B2 - 1u)) << 19) | s;
        sbk[p] = (unsigned char)b;
    }
    __syncthreads();
    const u32* row = aux1 + (size_t)bid * NB2;
    for (int p = tid; p < n; p += NT) {
        int b = sbk[p];
        rec1[bb1[b] + row[b] + ((u32)p - scn[b])] = srec[p];   // coalesced runs
    }
}

// ---- level-2 count over src-buckets + fused per-dl degree histogram
__global__ __launch_bounds__(NT) void k_count2deg(
        const u32* __restrict__ rec1, const u32* __restrict__ bb1,
        u32* __restrict__ counts2, u32* __restrict__ aux2,
        u32* __restrict__ degp) {
    __shared__ u32 hist[NB2];
    __shared__ u32 cnt[B2];
    int bid2 = blockIdx.x, b = bid2 / SPL, s = bid2 % SPL, tid = threadIdx.x;
    if (tid < NB2) hist[tid] = 0;
    for (int l = tid; l < B2; l += NT) cnt[l] = 0;
    __syncthreads();
    u32 base = bb1[b], len = bb1[b + 1] - base, per = (len + SPL - 1) / SPL;
    u32 s0 = base + (u32)s * per, end = base + len;
    u32 s1 = (s0 + per < end) ? (s0 + per) : end;
    for (u32 e = s0 + tid; e < s1; e += NT) {
        u32 r = __builtin_nontemporal_load(rec1 + e);
        atomicAdd(&hist[(r & SRC19) >> B2BITS], 1u);
        atomicAdd(&cnt[r >> 19], 1u);
    }
    __syncthreads();
    if (tid < NB2)
        aux2[(size_t)bid2 * NB2 + tid] =
            atomicAdd(&counts2[(size_t)b * NB2 + tid], hist[tid]);
    for (int l = tid; l < B2; l += NT)
        degp[((size_t)bid2 << B2BITS) + l] = cnt[l];
}

// ---- level-2 scan: per-bucket exclusive prefix over 123 -> tile table T
__global__ void k_scan2(const u32* __restrict__ counts2,
                        const u32* __restrict__ bb1, u32* __restrict__ T) {
    __shared__ u32 c[NB2];
    int b = blockIdx.x, tid = threadIdx.x;
    if (tid < NB2) c[tid] = counts2[(size_t)b * NB2 + tid];
    __syncthreads();
    if (tid == 0) {
        u32 a = bb1[b];
        for (int j = 0; j < NB2; ++j) { T[(size_t)b * NB2 + j] = a; a += c[j]; }
        if (b == 0) T[(size_t)NB2 * NB2] = bb1[NB2];
    }
}

// ---- degree reduce -> dis = rsqrt(deg+1), m1 = dis*x
__global__ void k_reduce_deg(const u32* __restrict__ degp,
                             const float* __restrict__ x,
                             float* __restrict__ dis, float* __restrict__ m1) {
    int node = blockIdx.x * NT + threadIdx.x;
    if (node >= N_NODES) return;
    int b = node >> B2BITS, l = node & (B2 - 1);
    u32 dsum = 0;
#pragma unroll
    for (int s = 0; s < SPL; ++s)
        dsum += degp[((size_t)(b * SPL + s) << B2BITS) + l];
    float r = rsqrtf((float)(dsum + 1u));   // +1 self-loop; always > 0
    dis[node] = r;
    m1[node] = r * x[node];
}

// ---- level-2 scatter: rec1 -> rec2 grouped by (dstBucket, srcBucket)
__global__ __launch_bounds__(NT) void k_scatter2(
        const u32* __restrict__ rec1, const u32* __restrict__ bb1,
        const u32* __restrict__ T, const u32* __restrict__ aux2,
        u32* __restrict__ rec2) {
    __shared__ u32 cur[NB2];
    int bid2 = blockIdx.x, b = bid2 / SPL, s = bid2 % SPL, tid = threadIdx.x;
    if (tid < NB2)
        cur[tid] = T[(size_t)b * NB2 + tid] + aux2[(size_t)bid2 * NB2 + tid];
    __syncthreads();
    u32 base = bb1[b], len = bb1[b + 1] - base, per = (len + SPL - 1) / SPL;
    u32 s0 = base + (u32)s * per, end = base + len;
    u32 s1 = (s0 + per < end) ? (s0 + per) : end;
    for (u32 e = s0 + tid; e < s1; e += NT) {
        u32 r = __builtin_nontemporal_load(rec1 + e);
        u32 j = (r & SRC19) >> B2BITS;
        u32 p = atomicAdd(&cur[j], 1u);
        rec2[p] = ((r & (B2 - 1u)) << B2BITS) | (r >> 19);   // sl<<12 | dl
    }
}

// ---- layer-1 aggregation: staged src window (LDS) + LDS acc. No gathers.
__global__ __launch_bounds__(NT) void k_layer1(
        const u32* __restrict__ rec2, const u32* __restrict__ T,
        const float* __restrict__ m1, float* __restrict__ accp) {
    __shared__ float win[B2];   // 16 KB
    __shared__ float acc[B2];   // 16 KB
    int bid2 = blockIdx.x, b = bid2 / SPL, s = bid2 % SPL, tid = threadIdx.x;
    for (int l = tid; l < B2; l += NT) acc[l] = 0.f;
    int j0 = s * JT, j1 = min(j0 + JT, NB2);
    for (int j = j0; j < j1; ++j) {
        u32 t0 = T[(size_t)b * NB2 + j], t1 = T[(size_t)b * NB2 + j + 1];
        if (t0 == t1) continue;
        __syncthreads();    // protect win from previous tile's readers
        ((float4*)win)[tid] = ((const float4*)(m1 + ((size_t)j << B2BITS)))[tid];
        __syncthreads();
        for (u32 e = t0 + tid; e < t1; e += NT) {
            u32 r = __builtin_nontemporal_load(rec2 + e);
            atomicAdd(&acc[r & (B2 - 1u)], win[r >> B2BITS]);
        }
    }
    __syncthreads();
    for (int l = tid; l < B2; l += NT)
        accp[((size_t)bid2 << B2BITS) + l] = acc[l];
}

// ---- reduce layer-1 partials, per-node MLP, write h2m + out(self+bias)
__global__ void k_reduce1(const float* __restrict__ accp,
                          const float* __restrict__ dis,
                          const float* __restrict__ m1,
                          const float* __restrict__ W1, const float* __restrict__ b1,
                          const float* __restrict__ W2, const float* __restrict__ b2,
                          float2* __restrict__ h2m, float2* __restrict__ out) {
    int node = blockIdx.x * NT + threadIdx.x;
    if (node >= N_NODES) return;
    int b = node >> B2BITS, l = node & (B2 - 1);
    float ssum = 0.f;
#pragma unroll
    for (int s = 0; s < SPL; ++s)
        ssum += accp[((size_t)(b * SPL + s) << B2BITS) + l];
    float d = dis[node];
    float sf = d * (ssum + m1[node]);
    float a0 = 0.f, a1 = 0.f;
#pragma unroll
    for (int k = 0; k < 8; ++k) {
        float h = fmaxf(W1[k] * sf + b1[k], 0.f);
        a0 += h * W2[2 * k + 0];
        a1 += h * W2[2 * k + 1];
    }
    h2m[node] = make_float2(d * a0, d * a1);
    out[node] = make_float2(b2[0] + d * d * a0, b2[1] + d * d * a1);
}

// ---- layer-2 aggregation: staged float2 window + two LDS acc planes
__global__ __launch_bounds__(NT) void k_layer2(
        const u32* __restrict__ rec2, const u32* __restrict__ T,
        const float2* __restrict__ h2m,
        float* __restrict__ px, float* __restrict__ py) {
    __shared__ float2 win2[B2];  // 32 KB
    __shared__ float ax[B2];     // 16 KB
    __shared__ float ay[B2];     // 16 KB  -> 64 KB total
    int bid2 = blockIdx.x, b = bid2 / SPL, s = bid2 % SPL, tid = threadIdx.x;
    for (int l = tid; l < B2; l += NT) { ax[l] = 0.f; ay[l] = 0.f; }
    int j0 = s * JT, j1 = min(j0 + JT, NB2);
    for (int j = j0; j < j1; ++j) {
        u32 t0 = T[(size_t)b * NB2 + j], t1 = T[(size_t)b * NB2 + j + 1];
        if (t0 == t1) continue;
        __syncthreads();
        const float4* srcw = (const float4*)(h2m + ((size_t)j << B2BITS));
        ((float4*)win2)[tid * 2]     = srcw[tid * 2];
        ((float4*)win2)[tid * 2 + 1] = srcw[tid * 2 + 1];
        __syncthreads();
        for (u32 e = t0 + tid; e < t1; e += NT) {
            u32 r = __builtin_nontemporal_load(rec2 + e);
            float2 v = win2[r >> B2BITS];
            u32 dl = r & (B2 - 1u);
            atomicAdd(&ax[dl], v.x);
            atomicAdd(&ay[dl], v.y);
        }
    }
    __syncthreads();
    for (int l = tid; l < B2; l += NT) {
        px[((size_t)bid2 << B2BITS) + l] = ax[l];
        py[((size_t)bid2 << B2BITS) + l] = ay[l];
    }
}

// ---- reduce layer-2 partials: out += dis * sum
__global__ void k_reduce2(const float* __restrict__ px, const float* __restrict__ py,
                          const float* __restrict__ dis, float2* __restrict__ out) {
    int node = blockIdx.x * NT + threadIdx.x;
    if (node >= N_NODES) return;
    int b = node >> B2BITS, l = node & (B2 - 1);
    float sx = 0.f, sy = 0.f;
#pragma unroll
    for (int s = 0; s < SPL; ++s) {
        size_t idx = ((size_t)(b * SPL + s) << B2BITS) + l;
        sx += px[idx];
        sy += py[idx];
    }
    float d = dis[node];
    float2 o = out[node];
    out[node] = make_float2(o.x + d * sx, o.y + d * sy);
}

// ===========================================================================
// MID PATH (R5): 1024-node dst buckets, unsorted gathers. Fallback only.
// ===========================================================================
#define NPB 1024
#define NBUCK ((N_NODES + NPB - 1) / NPB)
#define BIN_CHUNK 32768
#define BTB 1024
#define SRCMASK 0x3FFFFFu

typedef int  v4i __attribute__((ext_vector_type(4)));
typedef unsigned int v4u __attribute__((ext_vector_type(4)));
__device__ inline v4i nt_load4i(const int* p) { return __builtin_nontemporal_load((const v4i*)p); }
__device__ inline v4u nt_load4u(const u32* p) { return __builtin_nontemporal_load((const v4u*)p); }
__device__ inline int nt_load1i(const int* p) { return __builtin_nontemporal_load(p); }
__device__ inline u32 nt_load1u(const u32* p) { return __builtin_nontemporal_load(p); }

__global__ __launch_bounds__(BTB) void k_bin_count(
        const int* __restrict__ dst, int E, u32* __restrict__ counts, u32* __restrict__ aux) {
    __shared__ u32 hist[NBUCK];
    int tid = threadIdx.x, bid = blockIdx.x;
    for (int b = tid; b < NBUCK; b += BTB) hist[b] = 0;
    __syncthreads();
    int e0 = bid * BIN_CHUNK, e1 = min(E, e0 + BIN_CHUNK);
    for (int e = e0 + tid; e < e1; e += BTB)
        atomicAdd(&hist[(u32)nt_load1i(dst + e) >> 10], 1u);
    __syncthreads();
    u32* row = aux + (size_t)bid * NBUCK;
    for (int b = tid; b < NBUCK; b += BTB)
        row[b] = atomicAdd(&counts[b], hist[b]);
}
__global__ void k_scan(const u32* __restrict__ counts, u32* __restrict__ bucket_base) {
    __shared__ u32 sc[512];
    int tid = threadIdx.x;
    u32 v = (tid < NBUCK) ? counts[tid] : 0u;
    sc[tid] = v;
    __syncthreads();
    for (int off = 1; off < 512; off <<= 1) {
        u32 t = (tid >= off) ? sc[tid - off] : 0u;
        __syncthreads();
        sc[tid] += t;
        __syncthreads();
    }
    if (tid <= NBUCK) bucket_base[tid] = sc[tid] - v;
}
__global__ __launch_bounds__(BTB) void k_bin_scatter(
        const int* __restrict__ src, const int* __restrict__ dst, int E,
        const u32* __restrict__ bucket_base, const u32* __restrict__ aux,
        u32* __restrict__ rec) {
    __shared__ u32 cur[NBUCK];
    int tid = threadIdx.x, bid = blockIdx.x;
    const u32* row = aux + (size_t)bid * NBUCK;
    for (int b = tid; b < NBUCK; b += BTB) cur[b] = bucket_base[b] + row[b];
    __syncthreads();
    int e0 = bid * BIN_CHUNK, e1 = min(E, e0 + BIN_CHUNK);
    for (int e = e0 + tid; e < e1; e += BTB) {
        u32 d = (u32)nt_load1i(dst + e);
        u32 p = atomicAdd(&cur[d >> 10], 1u);
        rec[p] = ((d & (NPB - 1u)) << 22) | (u32)nt_load1i(src + e);
    }
}
__global__ __launch_bounds__(BTB) void k_deg_dis(
        const u32* __restrict__ rec, const u32* __restrict__ bucket_base,
        const float* __restrict__ x, float* __restrict__ dis, float* __restrict__ m1) {
    __shared__ u32 cnt[NPB];
    int tid = threadIdx.x, bid = blockIdx.x;
    for (int l = tid; l < NPB; l += BTB) cnt[l] = 0;
    __syncthreads();
    u32 e0 = bucket_base[bid], e1 = bucket_base[bid + 1];
    for (u32 e = e0 + tid; e < e1; e += BTB)
        atomicAdd(&cnt[nt_load1u(rec + e) >> 22], 1u);
    __syncthreads();
    int node0 = bid << 10;
    int nn = min(NPB, N_NODES - node0);
    for (int l = tid; l < nn; l += BTB) {
        int node = node0 + l;
        float r = rsqrtf((float)(cnt[l] + 1u));
        dis[node] = r;
        m1[node] = r * x[node];
    }
}
__global__ __launch_bounds__(BTB) void k_layer1_mid(
        const u32* __restrict__ rec, const u32* __restrict__ bucket_base,
        const float* __restrict__ dis, const float* __restrict__ m1,
        const float* __restrict__ W1, const float* __restrict__ b1,
        const float* __restrict__ W2, const float* __restrict__ b2,
        float2* __restrict__ h2m, float2* __restrict__ out) {
    __shared__ float acc[NPB];
    int tid = threadIdx.x, bid = blockIdx.x;
    for (int l = tid; l < NPB; l += BTB) acc[l] = 0.f;
    __syncthreads();
    u32 e0 = bucket_base[bid], e1 = bucket_base[bid + 1];
    for (u32 e = e0 + tid; e < e1; e += BTB) {
        u32 r = nt_load1u(rec + e);
        atomicAdd(&acc[r >> 22], m1[r & SRCMASK]);
    }
    __syncthreads();
    int node0 = bid << 10;
    int nn = min(NPB, N_NODES - node0);
    for (int l = tid; l < nn; l += BTB) {
        int node = node0 + l;
        float d = dis[node];
        float s = d * (acc[l] + m1[node]);
        float a0 = 0.f, a1 = 0.f;
#pragma unroll
        for (int k = 0; k < 8; ++k) {
            float h = fmaxf(W1[k] * s + b1[k], 0.f);
            a0 += h * W2[2 * k + 0];
            a1 += h * W2[2 * k + 1];
        }
        h2m[node] = make_float2(d * a0, d * a1);
        out[node] = make_float2(b2[0] + d * d * a0, b2[1] + d * d * a1);
    }
}
__global__ __launch_bounds__(BTB) void k_layer2_mid(
        const u32* __restrict__ rec, const u32* __restrict__ bucket_base,
        const float* __restrict__ dis, const float2* __restrict__ h2m,
        float2* __restrict__ out) {
    __shared__ float ax[NPB];
    __shared__ float ay[NPB];
    int tid = threadIdx.x, bid = blockIdx.x;
    for (int l = tid; l < NPB; l += BTB) { ax[l] = 0.f; ay[l] = 0.f; }
    __syncthreads();
    u32 e0 = bucket_base[bid], e1 = bucket_base[bid + 1];
    for (u32 e = e0 + tid; e < e1; e += BTB) {
        u32 r = nt_load1u(rec + e);
        float2 v = h2m[r & SRCMASK];
        atomicAdd(&ax[r >> 22], v.x);
        atomicAdd(&ay[r >> 22], v.y);
    }
    __syncthreads();
    int node0 = bid << 10;
    int nn = min(NPB, N_NODES - node0);
    for (int l = tid; l < nn; l += BTB) {
        int node = node0 + l;
        float d = dis[node];
        float2 o = out[node];
        out[node] = make_float2(o.x + d * ax[l], o.y + d * ay[l]);
    }
}

// ===========================================================================
extern "C" void kernel_launch(void* const* d_in, const int* in_sizes, int n_in,
                              void* d_out, int out_size, void* d_ws, size_t ws_size,
                              hipStream_t stream) {
    const float* x  = (const float*)d_in[0];
    const int*   ei = (const int*)d_in[1];   // [2,E]: src row then dst row
    const float* W1 = (const float*)d_in[2];
    const float* b1 = (const float*)d_in[3];
    const float* W2 = (const float*)d_in[4];
    const float* b2 = (const float*)d_in[5];

    const int N = N_NODES;
    const int E = in_sizes[1] / 2;
    const int* src = ei;
    const int* dst = ei + E;
    float* out = (float*)d_out;
    char* ws = (char*)d_ws;

    // ---------------- fast-path workspace ----------------
    const int nchunks1 = (E + C1 - 1) / C1;
    size_t off = 0;
    auto take = [&](size_t bytes) { size_t o = off; off = (off + bytes + 255) & ~(size_t)255; return o; };
    size_t off_bb1   = take((NB2 + 1) * 4);
    size_t off_cnt1  = take(NB2 * 4);
    size_t off_cnt2  = take((size_t)NB2 * NB2 * 4);
    size_t off_T     = take(((size_t)NB2 * NB2 + 1) * 4);
    size_t off_aux1  = take((size_t)nchunks1 * NB2 * 4);
    size_t off_aux2  = take((size_t)NB2 * SPL * NB2 * 4);
    size_t off_dis   = take((size_t)N * 4);
    size_t off_m1    = take((size_t)NPAD * 4);
    size_t off_h2m   = take((size_t)NPAD * 8);
    size_t off_bufA  = take((size_t)NB2 * SPL * B2 * 4);   // degp / accp
    size_t off_px    = take((size_t)NB2 * SPL * B2 * 4);
    size_t off_py    = take((size_t)NB2 * SPL * B2 * 4);
    size_t off_rec1  = take((size_t)E * 4);
    size_t off_rec2  = take((size_t)E * 4);
    size_t need_big  = off;

    if (ws_size >= need_big) {
        u32* bb1    = (u32*)(ws + off_bb1);
        u32* cnt1   = (u32*)(ws + off_cnt1);
        u32* cnt2   = (u32*)(ws + off_cnt2);
        u32* T      = (u32*)(ws + off_T);
        u32* aux1   = (u32*)(ws + off_aux1);
        u32* aux2   = (u32*)(ws + off_aux2);
        float* dis  = (float*)(ws + off_dis);
        float* m1   = (float*)(ws + off_m1);
        float2* h2m = (float2*)(ws + off_h2m);
        float* bufA = (float*)(ws + off_bufA);
        float* px   = (float*)(ws + off_px);
        float* py   = (float*)(ws + off_py);
        u32* rec1   = (u32*)(ws + off_rec1);
        u32* rec2   = (u32*)(ws + off_rec2);

        hipMemsetAsync(cnt1, 0, NB2 * 4, stream);
        hipMemsetAsync(cnt2, 0, (size_t)NB2 * NB2 * 4, stream);

        int nodeWG = (N + NT - 1) / NT;
        k_count1   <<<nchunks1,  NT, 0, stream>>>(dst, E, cnt1, aux1);
        k_scan1    <<<1,        128, 0, stream>>>(cnt1, bb1);
        k_scatter1 <<<nchunks1,  NT, 0, stream>>>(src, dst, E, bb1, aux1, rec1);
        k_count2deg<<<NB2 * SPL, NT, 0, stream>>>(rec1, bb1, cnt2, aux2, (u32*)bufA);
        k_scan2    <<<NB2,      128, 0, stream>>>(cnt2, bb1, T);
        k_reduce_deg<<<nodeWG,   NT, 0, stream>>>((u32*)bufA, x, dis, m1);
        k_scatter2 <<<NB2 * SPL, NT, 0, stream>>>(rec1, bb1, T, aux2, rec2);
        k_layer1   <<<NB2 * SPL, NT, 0, stream>>>(rec2, T, m1, bufA);
        k_reduce1  <<<nodeWG,    NT, 0, stream>>>(bufA, dis, m1, W1, b1, W2, b2,
                                                  h2m, (float2*)out);
        k_layer2   <<<NB2 * SPL, NT, 0, stream>>>(rec2, T, h2m, px, py);
        k_reduce2  <<<nodeWG,    NT, 0, stream>>>(px, py, dis, (float2*)out);
        return;
    }

    // ---------------- mid path (R5 fallback) ----------------
    const int nchunks = (E + BIN_CHUNK - 1) / BIN_CHUNK;
    size_t moff_counts = 0;
    size_t moff_bb     = 4096;
    size_t moff_aux    = 8192;
    size_t maux_bytes  = (size_t)nchunks * NBUCK * 4;
    size_t moff_dis    = (moff_aux + maux_bytes + 255) & ~(size_t)255;
    size_t moff_m1     = moff_dis + (size_t)N * 4;
    size_t moff_h2m    = moff_m1 + (size_t)N * 4;
    size_t moff_rec    = moff_h2m + (size_t)N * 8;

    u32* counts = (u32*)(ws + moff_counts);
    u32* bb     = (u32*)(ws + moff_bb);
    u32* aux    = (u32*)(ws + moff_aux);
    float* dis  = (float*)(ws + moff_dis);
    float* m1   = (float*)(ws + moff_m1);
    float2* h2m = (float2*)(ws + moff_h2m);
    u32* rec    = (u32*)(ws + moff_rec);

    hipMemsetAsync(counts, 0, NBUCK * 4, stream);
    k_bin_count  <<<nchunks, BTB, 0, stream>>>(dst, E, counts, aux);
    k_scan       <<<1,       512, 0, stream>>>(counts, bb);
    k_bin_scatter<<<nchunks, BTB, 0, stream>>>(src, dst, E, bb, aux, rec);
    k_deg_dis    <<<NBUCK,   BTB, 0, stream>>>(rec, bb, x, dis, m1);
    k_layer1_mid <<<NBUCK,   BTB, 0, stream>>>(rec, bb, dis, m1, W1, b1, W2, b2,
                                               h2m, (float2*)out);
    k_layer2_mid <<<NBUCK,   BTB, 0, stream>>>(rec, bb, dis, h2m, (float2*)out);
}

// Round 8
// 526.912 us; speedup vs baseline: 1.6449x; 1.5536x over previous
//
#include <hip/hip_runtime.h>

#define N_NODES 500000
typedef unsigned int u32;
typedef unsigned short u16;

// ===========================================================================
// R8 fast path: single-pass presorted scatter into fixed-capacity bucket
// regions (no count/scan passes), then R5-proven deg/layer1/layer2 kernels.
//   rec = dl10<<22 | src19   per 1024-node dst bucket.
// ===========================================================================
#define NPB    1024
#define NBUCK  ((N_NODES + NPB - 1) / NPB)   // 489
#define CAP    40960          // region capacity; E[fill]=32.7K, sigma~181 (45σ)
#define CH     8192           // edges per scatter chunk/WG
#define TB     1024
#define SRCMASK 0x3FFFFFu

typedef int  v4i __attribute__((ext_vector_type(4)));
typedef unsigned int v4u __attribute__((ext_vector_type(4)));
__device__ inline int  nt1i(const int* p) { return __builtin_nontemporal_load(p); }
__device__ inline u32  nt1u(const u32* p) { return __builtin_nontemporal_load(p); }
__device__ inline v4u  nt4u(const u32* p) { return __builtin_nontemporal_load((const v4u*)p); }

// ---- fused scatter: per-chunk LDS histogram + scan + presort + coalesced
//      writes into fixed bucket regions (base via 1 global atomic/(WG,bucket))
__global__ __launch_bounds__(TB) void k_scatter_fused(
        const int* __restrict__ src, const int* __restrict__ dst, int E,
        u32* __restrict__ cur_g, u32* __restrict__ rec) {
    __shared__ u32 srec[CH];        // 32 KB
    __shared__ u16 sbk[CH];         // 16 KB
    __shared__ u32 hist[NBUCK];     // ~2 KB
    __shared__ u32 sc[512];         // 2 KB
    __shared__ u32 scn_ex[NBUCK];
    __shared__ u32 cur2[NBUCK];
    __shared__ u32 gbase[NBUCK];
    int tid = threadIdx.x, bid = blockIdx.x;
    for (int b = tid; b < NBUCK; b += TB) hist[b] = 0;
    __syncthreads();
    int e0 = bid * CH, e1 = min(E, e0 + CH), n = e1 - e0;
    // pass 1: histogram
    for (int e = e0 + tid; e < e1; e += TB)
        atomicAdd(&hist[((u32)nt1i(dst + e)) >> 10], 1u);
    __syncthreads();
    // scan (Hillis-Steele over 512 slots; all threads hit barriers)
    if (tid < 512) sc[tid] = (tid < NBUCK) ? hist[tid] : 0u;
    __syncthreads();
    for (int off = 1; off < 512; off <<= 1) {
        u32 t = 0;
        if (tid < 512 && tid >= off) t = sc[tid - off];
        __syncthreads();
        if (tid < 512) sc[tid] += t;
        __syncthreads();
    }
    if (tid < NBUCK) {
        u32 ex = sc[tid] - hist[tid];
        scn_ex[tid] = ex;
        cur2[tid] = ex;
        gbase[tid] = hist[tid] ? atomicAdd(&cur_g[tid], hist[tid]) : 0u;
    }
    __syncthreads();
    // pass 2: presort into LDS
    for (int e = e0 + tid; e < e1; e += TB) {
        u32 d = (u32)nt1i(dst + e);
        u32 s = (u32)nt1i(src + e);
        u32 b = d >> 10;
        u32 p = atomicAdd(&cur2[b], 1u);
        srec[p] = ((d & (NPB - 1u)) << 22) | s;
        sbk[p] = (u16)b;
    }
    __syncthreads();
    // pass 3: coalesced run writes into bucket regions
    for (int p = tid; p < n; p += TB) {
        u32 b = sbk[p];
        u32 slot = gbase[b] + ((u32)p - scn_ex[b]);
        rec[(size_t)b * CAP + slot] = srec[p];
    }
}

// ---- per-bucket degree -> dis = rsqrt(deg+1), m1 = dis*x
__global__ __launch_bounds__(TB) void k_deg_dis(
        const u32* __restrict__ rec, const u32* __restrict__ cnt_g,
        const float* __restrict__ x,
        float* __restrict__ dis, float* __restrict__ m1) {
    __shared__ u32 cnt[NPB];
    int tid = threadIdx.x, bid = blockIdx.x;
    for (int l = tid; l < NPB; l += TB) cnt[l] = 0;
    __syncthreads();
    const u32* r0 = rec + (size_t)bid * CAP;
    u32 n = cnt_g[bid];
    u32 nv = n >> 2;
    for (u32 i = tid; i < nv; i += TB) {
        v4u r = nt4u(r0 + (i << 2));
        atomicAdd(&cnt[r.x >> 22], 1u);
        atomicAdd(&cnt[r.y >> 22], 1u);
        atomicAdd(&cnt[r.z >> 22], 1u);
        atomicAdd(&cnt[r.w >> 22], 1u);
    }
    for (u32 e = (nv << 2) + tid; e < n; e += TB)
        atomicAdd(&cnt[nt1u(r0 + e) >> 22], 1u);
    __syncthreads();
    int node0 = bid << 10;
    int nn = min(NPB, N_NODES - node0);
    for (int l = tid; l < nn; l += TB) {
        int node = node0 + l;
        float r = rsqrtf((float)(cnt[l] + 1u));   // +1 self-loop; always > 0
        dis[node] = r;
        m1[node] = r * x[node];
    }
}

// ---- layer-1: gather m1[src] + LDS acc; then per-node MLP -> h2m, out
__global__ __launch_bounds__(TB) void k_layer1(
        const u32* __restrict__ rec, const u32* __restrict__ cnt_g,
        const float* __restrict__ dis, const float* __restrict__ m1,
        const float* __restrict__ W1, const float* __restrict__ b1,
        const float* __restrict__ W2, const float* __restrict__ b2,
        float2* __restrict__ h2m, float2* __restrict__ out) {
    __shared__ float acc[NPB];
    int tid = threadIdx.x, bid = blockIdx.x;
    for (int l = tid; l < NPB; l += TB) acc[l] = 0.f;
    __syncthreads();
    const u32* r0 = rec + (size_t)bid * CAP;
    u32 n = cnt_g[bid];
    u32 nv = n >> 2;
    for (u32 i = tid; i < nv; i += TB) {
        v4u r = nt4u(r0 + (i << 2));
        float v0 = m1[r.x & SRCMASK];
        float v1 = m1[r.y & SRCMASK];
        float v2 = m1[r.z & SRCMASK];
        float v3 = m1[r.w & SRCMASK];
        atomicAdd(&acc[r.x >> 22], v0);
        atomicAdd(&acc[r.y >> 22], v1);
        atomicAdd(&acc[r.z >> 22], v2);
        atomicAdd(&acc[r.w >> 22], v3);
    }
    for (u32 e = (nv << 2) + tid; e < n; e += TB) {
        u32 r = nt1u(r0 + e);
        atomicAdd(&acc[r >> 22], m1[r & SRCMASK]);
    }
    __syncthreads();
    int node0 = bid << 10;
    int nn = min(NPB, N_NODES - node0);
    for (int l = tid; l < nn; l += TB) {
        int node = node0 + l;
        float d = dis[node];
        float s = d * (acc[l] + m1[node]);
        float a0 = 0.f, a1 = 0.f;
#pragma unroll
        for (int k = 0; k < 8; ++k) {
            float h = fmaxf(W1[k] * s + b1[k], 0.f);
            a0 += h * W2[2 * k + 0];
            a1 += h * W2[2 * k + 1];
        }
        h2m[node] = make_float2(d * a0, d * a1);                    // dis[src]*h2
        out[node] = make_float2(b2[0] + d * d * a0, b2[1] + d * d * a1);
    }
}

// ---- layer-2: gather h2m[src] + two LDS planes; out += dis*sum
__global__ __launch_bounds__(TB) void k_layer2(
        const u32* __restrict__ rec, const u32* __restrict__ cnt_g,
        const float* __restrict__ dis, const float2* __restrict__ h2m,
        float2* __restrict__ out) {
    __shared__ float ax[NPB];
    __shared__ float ay[NPB];
    int tid = threadIdx.x, bid = blockIdx.x;
    for (int l = tid; l < NPB; l += TB) { ax[l] = 0.f; ay[l] = 0.f; }
    __syncthreads();
    const u32* r0 = rec + (size_t)bid * CAP;
    u32 n = cnt_g[bid];
    u32 nv = n >> 2;
    for (u32 i = tid; i < nv; i += TB) {
        v4u r = nt4u(r0 + (i << 2));
        float2 v0 = h2m[r.x & SRCMASK];
        float2 v1 = h2m[r.y & SRCMASK];
        float2 v2 = h2m[r.z & SRCMASK];
        float2 v3 = h2m[r.w & SRCMASK];
        atomicAdd(&ax[r.x >> 22], v0.x);
        atomicAdd(&ay[r.x >> 22], v0.y);
        atomicAdd(&ax[r.y >> 22], v1.x);
        atomicAdd(&ay[r.y >> 22], v1.y);
        atomicAdd(&ax[r.z >> 22], v2.x);
        atomicAdd(&ay[r.z >> 22], v2.y);
        atomicAdd(&ax[r.w >> 22], v3.x);
        atomicAdd(&ay[r.w >> 22], v3.y);
    }
    for (u32 e = (nv << 2) + tid; e < n; e += TB) {
        u32 r = nt1u(r0 + e);
        float2 v = h2m[r & SRCMASK];
        atomicAdd(&ax[r >> 22], v.x);
        atomicAdd(&ay[r >> 22], v.y);
    }
    __syncthreads();
    int node0 = bid << 10;
    int nn = min(NPB, N_NODES - node0);
    for (int l = tid; l < nn; l += TB) {
        int node = node0 + l;
        float d = dis[node];
        float2 o = out[node];
        out[node] = make_float2(o.x + d * ax[l], o.y + d * ay[l]);
    }
}

// ===========================================================================
// Fallback path (R1): global atomics — only if ws too small (needs 10 MB).
// ===========================================================================
__global__ void f_count_deg(const int* __restrict__ dst, int E,
                            u32* __restrict__ deg) {
    int i = blockIdx.x * blockDim.x + threadIdx.x;
    int stride = gridDim.x * blockDim.x;
    for (int e = i; e < E; e += stride) atomicAdd(&deg[dst[e]], 1u);
}
__global__ void f_dis_sinit(const u32* __restrict__ deg, const float* __restrict__ x,
                            float* __restrict__ dis, float* __restrict__ s, int N) {
    int i = blockIdx.x * blockDim.x + threadIdx.x;
    if (i < N) {
        float r = rsqrtf((float)(deg[i] + 1u));
        dis[i] = r;
        s[i] = r * r * x[i];
    }
}
__global__ void f_agg1(const int* __restrict__ src, const int* __restrict__ dst,
                       int E, const float* __restrict__ dis,
                       const float* __restrict__ x, float* __restrict__ s) {
    int i = blockIdx.x * blockDim.x + threadIdx.x;
    int stride = gridDim.x * blockDim.x;
    for (int e = i; e < E; e += stride) {
        int sj = src[e], dj = dst[e];
        atomicAdd(&s[dj], dis[sj] * dis[dj] * x[sj]);
    }
}
__global__ void f_node2(const float* __restrict__ s, const float* __restrict__ dis,
                        const float* __restrict__ W1, const float* __restrict__ b1,
                        const float* __restrict__ W2, const float* __restrict__ b2,
                        float2* __restrict__ h2, float2* __restrict__ out, int N) {
    int i = blockIdx.x * blockDim.x + threadIdx.x;
    if (i >= N) return;
    float si = s[i];
    float a0 = 0.f, a1 = 0.f;
#pragma unroll
    for (int k = 0; k < 8; ++k) {
        float hk = fmaxf(W1[k] * si + b1[k], 0.f);
        a0 += hk * W2[2 * k + 0];
        a1 += hk * W2[2 * k + 1];
    }
    h2[i] = make_float2(a0, a1);
    float r2 = dis[i] * dis[i];
    out[i] = make_float2(b2[0] + r2 * a0, b2[1] + r2 * a1);
}
__global__ void f_agg2(const int* __restrict__ src, const int* __restrict__ dst,
                       int E, const float* __restrict__ dis,
                       const float2* __restrict__ h2, float* __restrict__ out) {
    int i = blockIdx.x * blockDim.x + threadIdx.x;
    int stride = gridDim.x * blockDim.x;
    for (int e = i; e < E; e += stride) {
        int sj = src[e], dj = dst[e];
        float nm = dis[sj] * dis[dj];
        float2 v = h2[sj];
        atomicAdd(&out[2 * dj + 0], nm * v.x);
        atomicAdd(&out[2 * dj + 1], nm * v.y);
    }
}

// ===========================================================================
extern "C" void kernel_launch(void* const* d_in, const int* in_sizes, int n_in,
                              void* d_out, int out_size, void* d_ws, size_t ws_size,
                              hipStream_t stream) {
    const float* x  = (const float*)d_in[0];
    const int*   ei = (const int*)d_in[1];   // [2,E]: src row, then dst row
    const float* W1 = (const float*)d_in[2];
    const float* b1 = (const float*)d_in[3];
    const float* W2 = (const float*)d_in[4];
    const float* b2 = (const float*)d_in[5];

    const int N = N_NODES;
    const int E = in_sizes[1] / 2;
    const int* src = ei;
    const int* dst = ei + E;
    float* out = (float*)d_out;
    char* ws = (char*)d_ws;

    // ---- fast-path workspace ----
    size_t off = 0;
    auto take = [&](size_t bytes) { size_t o = off; off = (off + bytes + 255) & ~(size_t)255; return o; };
    size_t off_cur  = take(NBUCK * 4);
    size_t off_dis  = take((size_t)N * 4);
    size_t off_m1   = take((size_t)N * 4);
    size_t off_h2m  = take((size_t)N * 8);
    size_t off_rec  = take((size_t)NBUCK * CAP * 4 + 16);   // 80 MB
    size_t need     = off;

    if (ws_size >= need) {
        u32* cur_g  = (u32*)(ws + off_cur);
        float* dis  = (float*)(ws + off_dis);
        float* m1   = (float*)(ws + off_m1);
        float2* h2m = (float2*)(ws + off_h2m);
        u32* rec    = (u32*)(ws + off_rec);

        hipMemsetAsync(cur_g, 0, NBUCK * 4, stream);
        const int nchunks = (E + CH - 1) / CH;
        k_scatter_fused<<<nchunks, TB, 0, stream>>>(src, dst, E, cur_g, rec);
        k_deg_dis      <<<NBUCK,   TB, 0, stream>>>(rec, cur_g, x, dis, m1);
        k_layer1       <<<NBUCK,   TB, 0, stream>>>(rec, cur_g, dis, m1,
                                                    W1, b1, W2, b2,
                                                    h2m, (float2*)out);
        k_layer2       <<<NBUCK,   TB, 0, stream>>>(rec, cur_g, dis, h2m,
                                                    (float2*)out);
        return;
    }

    // ---- fallback: R1 global-atomic path (10 MB ws) ----
    u32* deg   = (u32*)(ws);
    float* dis = (float*)(ws + (size_t)N * 4);
    float* s   = (float*)(ws + (size_t)N * 8);
    float2* h2 = (float2*)(ws + (size_t)N * 12);
    hipMemsetAsync(deg, 0, (size_t)N * 4, stream);
    int nodeBlocks = (N + 255) / 256;
    int edgeBlocks = (E + 255) / 256;
    f_count_deg<<<edgeBlocks, 256, 0, stream>>>(dst, E, deg);
    f_dis_sinit<<<nodeBlocks, 256, 0, stream>>>(deg, x, dis, s, N);
    f_agg1     <<<edgeBlocks, 256, 0, stream>>>(src, dst, E, dis, x, s);
    f_node2    <<<nodeBlocks, 256, 0, stream>>>(s, dis, W1, b1, W2, b2, h2,
                                                (float2*)out, N);
    f_agg2     <<<edgeBlocks, 256, 0, stream>>>(src, dst, E, dis, h2, out);
}

// Round 9
// 521.205 us; speedup vs baseline: 1.6629x; 1.0109x over previous
//
#include <hip/hip_runtime.h>

#define N_NODES 500000
typedef unsigned int u32;
typedef unsigned short u16;

// ===========================================================================
// R9 fast path: fixed-capacity presorted scatter (register-cached edges),
// then deg/layer1/layer2 with 512-node buckets (977 WGs, 8 waves each) for
// high occupancy — divergent-gather wall is MSHR×latency bound, scales with
// resident waves.
//   rec = dl9<<19 | src19   per 512-node dst bucket.
// ===========================================================================
#define NPB    512
#define NBUCK  ((N_NODES + NPB - 1) / NPB)   // 977
#define CAP    20480          // region capacity; E[fill]=16384, sigma~128 (32σ)
#define CH     8192           // edges per scatter chunk/WG
#define EPT    8              // edges per thread in scatter (CH / 1024)
#define STB    1024           // scatter block
#define LTB    512            // layer/deg block
#define SRC19  0x7FFFFu

typedef unsigned int v4u __attribute__((ext_vector_type(4)));
__device__ inline int  nt1i(const int* p) { return __builtin_nontemporal_load(p); }
__device__ inline u32  nt1u(const u32* p) { return __builtin_nontemporal_load(p); }
__device__ inline v4u  nt4u(const u32* p) { return __builtin_nontemporal_load((const v4u*)p); }

// ---- fused scatter: edges register-cached; LDS histogram + scan + presort;
//      coalesced run writes into fixed bucket regions.
__global__ __launch_bounds__(STB) void k_scatter_fused(
        const int* __restrict__ src, const int* __restrict__ dst, int E,
        u32* __restrict__ cur_g, u32* __restrict__ rec) {
    __shared__ u32 srec[CH];        // 32 KB
    __shared__ u16 sbk[CH];         // 16 KB
    __shared__ u32 hist[NBUCK];     // 3.9 KB
    __shared__ u32 sc[1024];        // 4 KB
    __shared__ u32 scn_ex[NBUCK];
    __shared__ u32 cur2[NBUCK];
    __shared__ u32 gbase[NBUCK];
    int tid = threadIdx.x, bid = blockIdx.x;
    for (int b = tid; b < NBUCK; b += STB) hist[b] = 0;
    __syncthreads();
    int e0 = bid * CH, e1 = min(E, e0 + CH), n = e1 - e0;
    // load edges into registers (coalesced), histogram
    u32 dv[EPT], sv[EPT];
#pragma unroll
    for (int k = 0; k < EPT; ++k) {
        int e = e0 + (k << 10) + tid;
        if (e < e1) {
            dv[k] = (u32)nt1i(dst + e);
            sv[k] = (u32)nt1i(src + e);
            atomicAdd(&hist[dv[k] >> 9], 1u);
        }
    }
    __syncthreads();
    // scan over 1024 slots (Hillis-Steele)
    sc[tid] = (tid < NBUCK) ? hist[tid] : 0u;
    __syncthreads();
    for (int off = 1; off < 1024; off <<= 1) {
        u32 t = (tid >= off) ? sc[tid - off] : 0u;
        __syncthreads();
        sc[tid] += t;
        __syncthreads();
    }
    if (tid < NBUCK) {
        u32 ex = sc[tid] - hist[tid];
        scn_ex[tid] = ex;
        cur2[tid] = ex;
        gbase[tid] = hist[tid] ? atomicAdd(&cur_g[tid], hist[tid]) : 0u;
    }
    __syncthreads();
    // presort into LDS from registers
#pragma unroll
    for (int k = 0; k < EPT; ++k) {
        int e = e0 + (k << 10) + tid;
        if (e < e1) {
            u32 b = dv[k] >> 9;
            u32 p = atomicAdd(&cur2[b], 1u);
            srec[p] = ((dv[k] & (NPB - 1u)) << 19) | sv[k];
            sbk[p] = (u16)b;
        }
    }
    __syncthreads();
    // coalesced run writes into bucket regions
    for (int p = tid; p < n; p += STB) {
        u32 b = sbk[p];
        u32 slot = gbase[b] + ((u32)p - scn_ex[b]);
        rec[(size_t)b * CAP + slot] = srec[p];
    }
}

// ---- per-bucket degree -> dis = rsqrt(deg+1), m1 = dis*x
__global__ __launch_bounds__(LTB) void k_deg_dis(
        const u32* __restrict__ rec, const u32* __restrict__ cnt_g,
        const float* __restrict__ x,
        float* __restrict__ dis, float* __restrict__ m1) {
    __shared__ u32 cnt[NPB];
    int tid = threadIdx.x, bid = blockIdx.x;
    for (int l = tid; l < NPB; l += LTB) cnt[l] = 0;
    __syncthreads();
    const u32* r0 = rec + (size_t)bid * CAP;
    u32 n = cnt_g[bid];
    u32 nv = n >> 2;
    for (u32 i = tid; i < nv; i += LTB) {
        v4u r = nt4u(r0 + (i << 2));
        atomicAdd(&cnt[r.x >> 19], 1u);
        atomicAdd(&cnt[r.y >> 19], 1u);
        atomicAdd(&cnt[r.z >> 19], 1u);
        atomicAdd(&cnt[r.w >> 19], 1u);
    }
    for (u32 e = (nv << 2) + tid; e < n; e += LTB)
        atomicAdd(&cnt[nt1u(r0 + e) >> 19], 1u);
    __syncthreads();
    int node0 = bid << 9;
    int nn = min(NPB, N_NODES - node0);
    for (int l = tid; l < nn; l += LTB) {
        int node = node0 + l;
        float r = rsqrtf((float)(cnt[l] + 1u));   // +1 self-loop; always > 0
        dis[node] = r;
        m1[node] = r * x[node];
    }
}

// ---- layer-1: gather m1[src] + LDS acc; then per-node MLP -> h2m, out
__global__ __launch_bounds__(LTB) void k_layer1(
        const u32* __restrict__ rec, const u32* __restrict__ cnt_g,
        const float* __restrict__ dis, const float* __restrict__ m1,
        const float* __restrict__ W1, const float* __restrict__ b1,
        const float* __restrict__ W2, const float* __restrict__ b2,
        float2* __restrict__ h2m, float2* __restrict__ out) {
    __shared__ float acc[NPB];
    int tid = threadIdx.x, bid = blockIdx.x;
    for (int l = tid; l < NPB; l += LTB) acc[l] = 0.f;
    __syncthreads();
    const u32* r0 = rec + (size_t)bid * CAP;
    u32 n = cnt_g[bid];
    u32 nv = n >> 2;
    for (u32 i = tid; i < nv; i += LTB) {
        v4u r = nt4u(r0 + (i << 2));
        float v0 = m1[r.x & SRC19];
        float v1 = m1[r.y & SRC19];
        float v2 = m1[r.z & SRC19];
        float v3 = m1[r.w & SRC19];
        atomicAdd(&acc[r.x >> 19], v0);
        atomicAdd(&acc[r.y >> 19], v1);
        atomicAdd(&acc[r.z >> 19], v2);
        atomicAdd(&acc[r.w >> 19], v3);
    }
    for (u32 e = (nv << 2) + tid; e < n; e += LTB) {
        u32 r = nt1u(r0 + e);
        atomicAdd(&acc[r >> 19], m1[r & SRC19]);
    }
    __syncthreads();
    int node0 = bid << 9;
    int nn = min(NPB, N_NODES - node0);
    for (int l = tid; l < nn; l += LTB) {
        int node = node0 + l;
        float d = dis[node];
        float s = d * (acc[l] + m1[node]);
        float a0 = 0.f, a1 = 0.f;
#pragma unroll
        for (int k = 0; k < 8; ++k) {
            float h = fmaxf(W1[k] * s + b1[k], 0.f);
            a0 += h * W2[2 * k + 0];
            a1 += h * W2[2 * k + 1];
        }
        h2m[node] = make_float2(d * a0, d * a1);                    // dis[src]*h2
        out[node] = make_float2(b2[0] + d * d * a0, b2[1] + d * d * a1);
    }
}

// ---- layer-2: gather h2m[src] + two LDS planes; out += dis*sum
__global__ __launch_bounds__(LTB) void k_layer2(
        const u32* __restrict__ rec, const u32* __restrict__ cnt_g,
        const float* __restrict__ dis, const float2* __restrict__ h2m,
        float2* __restrict__ out) {
    __shared__ float ax[NPB];
    __shared__ float ay[NPB];
    int tid = threadIdx.x, bid = blockIdx.x;
    for (int l = tid; l < NPB; l += LTB) { ax[l] = 0.f; ay[l] = 0.f; }
    __syncthreads();
    const u32* r0 = rec + (size_t)bid * CAP;
    u32 n = cnt_g[bid];
    u32 nv = n >> 2;
    for (u32 i = tid; i < nv; i += LTB) {
        v4u r = nt4u(r0 + (i << 2));
        float2 v0 = h2m[r.x & SRC19];
        float2 v1 = h2m[r.y & SRC19];
        float2 v2 = h2m[r.z & SRC19];
        float2 v3 = h2m[r.w & SRC19];
        atomicAdd(&ax[r.x >> 19], v0.x);
        atomicAdd(&ay[r.x >> 19], v0.y);
        atomicAdd(&ax[r.y >> 19], v1.x);
        atomicAdd(&ay[r.y >> 19], v1.y);
        atomicAdd(&ax[r.z >> 19], v2.x);
        atomicAdd(&ay[r.z >> 19], v2.y);
        atomicAdd(&ax[r.w >> 19], v3.x);
        atomicAdd(&ay[r.w >> 19], v3.y);
    }
    for (u32 e = (nv << 2) + tid; e < n; e += LTB) {
        u32 r = nt1u(r0 + e);
        float2 v = h2m[r & SRC19];
        atomicAdd(&ax[r >> 19], v.x);
        atomicAdd(&ay[r >> 19], v.y);
    }
    __syncthreads();
    int node0 = bid << 9;
    int nn = min(NPB, N_NODES - node0);
    for (int l = tid; l < nn; l += LTB) {
        int node = node0 + l;
        float d = dis[node];
        float2 o = out[node];
        out[node] = make_float2(o.x + d * ax[l], o.y + d * ay[l]);
    }
}

// ===========================================================================
// Fallback path (R1): global atomics — only if ws too small (needs 10 MB).
// ===========================================================================
__global__ void f_count_deg(const int* __restrict__ dst, int E,
                            u32* __restrict__ deg) {
    int i = blockIdx.x * blockDim.x + threadIdx.x;
    int stride = gridDim.x * blockDim.x;
    for (int e = i; e < E; e += stride) atomicAdd(&deg[dst[e]], 1u);
}
__global__ void f_dis_sinit(const u32* __restrict__ deg, const float* __restrict__ x,
                            float* __restrict__ dis, float* __restrict__ s, int N) {
    int i = blockIdx.x * blockDim.x + threadIdx.x;
    if (i < N) {
        float r = rsqrtf((float)(deg[i] + 1u));
        dis[i] = r;
        s[i] = r * r * x[i];
    }
}
__global__ void f_agg1(const int* __restrict__ src, const int* __restrict__ dst,
                       int E, const float* __restrict__ dis,
                       const float* __restrict__ x, float* __restrict__ s) {
    int i = blockIdx.x * blockDim.x + threadIdx.x;
    int stride = gridDim.x * blockDim.x;
    for (int e = i; e < E; e += stride) {
        int sj = src[e], dj = dst[e];
        atomicAdd(&s[dj], dis[sj] * dis[dj] * x[sj]);
    }
}
__global__ void f_node2(const float* __restrict__ s, const float* __restrict__ dis,
                        const float* __restrict__ W1, const float* __restrict__ b1,
                        const float* __restrict__ W2, const float* __restrict__ b2,
                        float2* __restrict__ h2, float2* __restrict__ out, int N) {
    int i = blockIdx.x * blockDim.x + threadIdx.x;
    if (i >= N) return;
    float si = s[i];
    float a0 = 0.f, a1 = 0.f;
#pragma unroll
    for (int k = 0; k < 8; ++k) {
        float hk = fmaxf(W1[k] * si + b1[k], 0.f);
        a0 += hk * W2[2 * k + 0];
        a1 += hk * W2[2 * k + 1];
    }
    h2[i] = make_float2(a0, a1);
    float r2 = dis[i] * dis[i];
    out[i] = make_float2(b2[0] + r2 * a0, b2[1] + r2 * a1);
}
__global__ void f_agg2(const int* __restrict__ src, const int* __restrict__ dst,
                       int E, const float* __restrict__ dis,
                       const float2* __restrict__ h2, float* __restrict__ out) {
    int i = blockIdx.x * blockDim.x + threadIdx.x;
    int stride = gridDim.x * blockDim.x;
    for (int e = i; e < E; e += stride) {
        int sj = src[e], dj = dst[e];
        float nm = dis[sj] * dis[dj];
        float2 v = h2[sj];
        atomicAdd(&out[2 * dj + 0], nm * v.x);
        atomicAdd(&out[2 * dj + 1], nm * v.y);
    }
}

// ===========================================================================
extern "C" void kernel_launch(void* const* d_in, const int* in_sizes, int n_in,
                              void* d_out, int out_size, void* d_ws, size_t ws_size,
                              hipStream_t stream) {
    const float* x  = (const float*)d_in[0];
    const int*   ei = (const int*)d_in[1];   // [2,E]: src row, then dst row
    const float* W1 = (const float*)d_in[2];
    const float* b1 = (const float*)d_in[3];
    const float* W2 = (const float*)d_in[4];
    const float* b2 = (const float*)d_in[5];

    const int N = N_NODES;
    const int E = in_sizes[1] / 2;
    const int* src = ei;
    const int* dst = ei + E;
    float* out = (float*)d_out;
    char* ws = (char*)d_ws;

    // ---- fast-path workspace ----
    size_t off = 0;
    auto take = [&](size_t bytes) { size_t o = off; off = (off + bytes + 255) & ~(size_t)255; return o; };
    size_t off_cur  = take(NBUCK * 4);
    size_t off_dis  = take((size_t)N * 4);
    size_t off_m1   = take((size_t)N * 4);
    size_t off_h2m  = take((size_t)N * 8);
    size_t off_rec  = take((size_t)NBUCK * CAP * 4 + 16);   // ~80 MB
    size_t need     = off;

    if (ws_size >= need) {
        u32* cur_g  = (u32*)(ws + off_cur);
        float* dis  = (float*)(ws + off_dis);
        float* m1   = (float*)(ws + off_m1);
        float2* h2m = (float2*)(ws + off_h2m);
        u32* rec    = (u32*)(ws + off_rec);

        hipMemsetAsync(cur_g, 0, NBUCK * 4, stream);
        const int nchunks = (E + CH - 1) / CH;
        k_scatter_fused<<<nchunks, STB, 0, stream>>>(src, dst, E, cur_g, rec);
        k_deg_dis      <<<NBUCK,   LTB, 0, stream>>>(rec, cur_g, x, dis, m1);
        k_layer1       <<<NBUCK,   LTB, 0, stream>>>(rec, cur_g, dis, m1,
                                                     W1, b1, W2, b2,
                                                     h2m, (float2*)out);
        k_layer2       <<<NBUCK,   LTB, 0, stream>>>(rec, cur_g, dis, h2m,
                                                     (float2*)out);
        return;
    }

    // ---- fallback: R1 global-atomic path (10 MB ws) ----
    u32* deg    = (u32*)(ws);
    float* dis  = (float*)(ws + (size_t)N * 4);
    float* s    = (float*)(ws + (size_t)N * 8);
    float2* h2  = (float2*)(ws + (size_t)N * 12);
    hipMemsetAsync(deg, 0, (size_t)N * 4, stream);
    int nodeBlocks = (N + 255) / 256;
    int edgeBlocks = (E + 255) / 256;
    f_count_deg<<<edgeBlocks, 256, 0, stream>>>(dst, E, deg);
    f_dis_sinit<<<nodeBlocks, 256, 0, stream>>>(deg, x, dis, s, N);
    f_agg1     <<<edgeBlocks, 256, 0, stream>>>(src, dst, E, dis, x, s);
    f_node2    <<<nodeBlocks, 256, 0, stream>>>(s, dis, W1, b1, W2, b2, h2,
                                                (float2*)out, N);
    f_agg2     <<<edgeBlocks, 256, 0, stream>>>(src, dst, E, dis, h2, out);
}